// Round 13
// baseline (4858.839 us; speedup 1.0000x reference)
//
#include <hip/hip_runtime.h>
#include <cstdint>
#include <cstddef>

typedef __attribute__((ext_vector_type(4))) int int32x4;
typedef __attribute__((ext_vector_type(16))) int int32x16;

#define DEVI __device__ __forceinline__

constexpr int M = 16384;
constexpr int N = 11008;
constexpr int K = 4096;
constexpr int BM = 256, BN = 256, BK = 64;
constexpr int NT_M = M / BM;                 // 64
constexpr int NT_N = N / BN;                 // 43
constexpr int NTILES = K / BK;               // 64
constexpr int NWG = NT_M * NT_N;             // 2752 = 8 * 344
constexpr int TILE_BYTES = BM * BK;          // 16 KB per tensor per slot

DEVI void gload_lds16(const void* gsrc, void* ldst) {
  __builtin_amdgcn_global_load_lds(
      (const __attribute__((address_space(1))) unsigned int*)gsrc,
      (__attribute__((address_space(3))) unsigned int*)ldst,
      16, 0, 0);
}

// ---- weight repack: int32 (harness int convention) -> int8 ----
__global__ __launch_bounds__(256) void pack_w_kernel(const int* __restrict__ w32,
                                                     signed char* __restrict__ w8) {
  const int idx = blockIdx.x * 256 + threadIdx.x;
  const int total4 = N * K / 4;
  if (idx < total4) {
    const int4 v = ((const int4*)w32)[idx];
    ((int*)w8)[idx] = (v.x & 255) | ((v.y & 255) << 8) |
                      ((v.z & 255) << 16) | ((v.w & 255) << 24);
  }
}

// ---- per-row symmetric int8 quantization of X ----
__global__ __launch_bounds__(256) void quant_x_kernel(const float* __restrict__ x,
                                                      signed char* __restrict__ xq,
                                                      float* __restrict__ sx) {
  const int row = blockIdx.x;
  const int t = threadIdx.x;
  const float4* xr = (const float4*)(x + (size_t)row * K);
  float4 v[4];
  float amax = 0.f;
  #pragma unroll
  for (int c = 0; c < 4; ++c) {
    v[c] = xr[c * 256 + t];
    amax = fmaxf(amax, fmaxf(fmaxf(fabsf(v[c].x), fabsf(v[c].y)),
                             fmaxf(fabsf(v[c].z), fabsf(v[c].w))));
  }
  __shared__ float red[256];
  red[t] = amax;
  __syncthreads();
  #pragma unroll
  for (int s = 128; s >= 1; s >>= 1) {
    if (t < s) red[t] = fmaxf(red[t], red[t + s]);
    __syncthreads();
  }
  const float am = fmaxf(red[0], 1e-20f);
  const float inv = 127.f / am;
  if (t == 0) sx[row] = am * (1.f / 127.f);
  int* xq32 = (int*)(xq + (size_t)row * K);
  #pragma unroll
  for (int c = 0; c < 4; ++c) {
    int q0 = min(127, max(-127, __float2int_rn(v[c].x * inv)));
    int q1 = min(127, max(-127, __float2int_rn(v[c].y * inv)));
    int q2 = min(127, max(-127, __float2int_rn(v[c].z * inv)));
    int q3 = min(127, max(-127, __float2int_rn(v[c].w * inv)));
    xq32[c * 256 + t] = (q0 & 255) | ((q1 & 255) << 8) |
                        ((q2 & 255) << 16) | ((q3 & 255) << 24);
  }
}

// ---- ABLATION: three variants of the R6 structure ----
// V=1: MFMA-only x4 (no LDS reads / stage / barriers in loop) -> pure
//      matrix-pipe wall at 2 waves/SIMD. Floor 1.34 ms @ 100% util.
// V=2: DSL+lgkm+MFMA x4 (R6 reg-dbuf read stream; no stage/vmcnt/barrier)
//      -> adds LDS-read serialization.
// V=3: full R6 (correct math; launched LAST so d_out is valid).
// V1/V2 compute garbage on purpose; V3 overwrites all of d_out.
template <int V>
__global__ __launch_bounds__(512, 2) void gemm_i8_kernel(const signed char* __restrict__ aq,
                                                         const signed char* __restrict__ wq,
                                                         const float* __restrict__ sx,
                                                         const float* __restrict__ sw,
                                                         float* __restrict__ out) {
  extern __shared__ signed char smem[];            // 131072 B: 4 slots x 32 KB
  signed char* lsA = smem;
  signed char* lsB = smem + 4 * TILE_BYTES;

  const int t = threadIdx.x;
  const int w = t >> 6;
  const int l = t & 63;

  const int bid = blockIdx.x;
  const int wg = (bid & 7) * (NWG / 8) + (bid >> 3);
  const int mt = wg / NT_N;
  const int nt = wg % NT_N;
  const int m0 = mt * BM, n0 = nt * BN;

  const bool stA = (w < 4);
  const signed char* src[4];
  int loff[4];
  #pragma unroll
  for (int c = 0; c < 4; ++c) {
    const int q = (w & 3) * 4 + c;
    const int row = (q & 3) * 64 + l;
    const int s = q >> 2;
    const signed char* base = stA ? (aq + (size_t)(m0 + row) * K)
                                  : (wq + (size_t)(n0 + row) * K);
    src[c] = base + s * 16;
    loff[c] = q * 1024;
  }

#define STAGE(tile)                                                           \
  {                                                                           \
    signed char* lbase = (stA ? lsA : lsB) + ((tile) & 3) * TILE_BYTES;       \
    const int koff = (tile) * BK;                                             \
    gload_lds16(src[0] + koff, lbase + loff[0]);                              \
    gload_lds16(src[1] + koff, lbase + loff[1]);                              \
    gload_lds16(src[2] + koff, lbase + loff[2]);                              \
    gload_lds16(src[3] + koff, lbase + loff[3]);                              \
  }

  const int wm = w >> 2, wn = w & 3;
  const int lk = l >> 5;
  const int lr = l & 31;
  int aOff[4], bOff[2];
  #pragma unroll
  for (int i = 0; i < 4; ++i)
    aOff[i] = lk * 4096 + (wm * 128 + i * 32 + lr) * 16;
  #pragma unroll
  for (int j = 0; j < 2; ++j)
    bOff[j] = lk * 4096 + (wn * 64 + j * 32 + lr) * 16;

  int32x16 acc[4][2] = {};
  int32x4 af0[4], bf0[2], af1[4], bf1[2];

#define DSL(tile, sub, AF, BF)                                                \
  {                                                                           \
    const signed char* pA = lsA + ((tile) & 3) * TILE_BYTES + (sub) * 8192;   \
    const signed char* pB = lsB + ((tile) & 3) * TILE_BYTES + (sub) * 8192;   \
    AF[0] = *(const int32x4*)(pA + aOff[0]);                                  \
    AF[1] = *(const int32x4*)(pA + aOff[1]);                                  \
    AF[2] = *(const int32x4*)(pA + aOff[2]);                                  \
    AF[3] = *(const int32x4*)(pA + aOff[3]);                                  \
    BF[0] = *(const int32x4*)(pB + bOff[0]);                                  \
    BF[1] = *(const int32x4*)(pB + bOff[1]);                                  \
  }

#define MFMA8(AF, BF)                                                         \
  __builtin_amdgcn_s_setprio(1);                                              \
  {                                                                           \
    _Pragma("unroll")                                                         \
    for (int i = 0; i < 4; ++i) {                                             \
      acc[i][0] = __builtin_amdgcn_mfma_i32_32x32x32_i8(AF[i], BF[0],         \
                                                        acc[i][0], 0, 0, 0);  \
      acc[i][1] = __builtin_amdgcn_mfma_i32_32x32x32_i8(AF[i], BF[1],         \
                                                        acc[i][1], 0, 0, 0);  \
    }                                                                         \
  }                                                                           \
  __builtin_amdgcn_s_setprio(0);

#define WAITV(n) asm volatile("s_waitcnt vmcnt(" #n ")" ::: "memory");
#define WLGKM(n)                                                              \
  asm volatile("s_waitcnt lgkmcnt(" #n ")" ::: "memory");                     \
  __builtin_amdgcn_sched_barrier(0);
#define BAR() __builtin_amdgcn_s_barrier();

#define ITER(tt)                                                              \
  WAITV(4)                                                                    \
  BAR()                                                                       \
  STAGE(tt + 3)                                                               \
  DSL(tt, 1, af1, bf1)                                                        \
  WLGKM(6)                                                                    \
  MFMA8(af0, bf0)                                                             \
  DSL(tt + 1, 0, af0, bf0)                                                    \
  WLGKM(6)                                                                    \
  MFMA8(af1, bf1)

  if constexpr (V == 1) {
    // Pure MFMA wall: frags loaded once, then 4 x 64 tile-iters of 16 MFMA.
    STAGE(0)
    WAITV(0)
    BAR()
    DSL(0, 0, af0, bf0)
    DSL(0, 1, af1, bf1)
    WLGKM(0)
    #pragma unroll 1
    for (int r = 0; r < 4; ++r) {
      #pragma unroll 1
      for (int tt = 0; tt < 64; ++tt) {
        MFMA8(af0, bf0)
        MFMA8(af1, bf1)
      }
    }
  } else if constexpr (V == 2) {
    // LDS-read stream + MFMA (R6 reg-dbuf), no stage/vmcnt/barrier in loop.
    STAGE(0)
    WAITV(0)
    BAR()
    #pragma unroll 1
    for (int r = 0; r < 4; ++r) {
      DSL(0, 0, af0, bf0)
      #pragma unroll 4
      for (int tt = 0; tt < 64; ++tt) {
        DSL(tt, 1, af1, bf1)
        WLGKM(6)
        MFMA8(af0, bf0)
        DSL(tt + 1, 0, af0, bf0)
        WLGKM(6)
        MFMA8(af1, bf1)
      }
    }
  } else {
    // Full R6 (correct).
    STAGE(0) STAGE(1) STAGE(2)
    WAITV(8)
    BAR()
    DSL(0, 0, af0, bf0)
    #pragma unroll 4
    for (int tb = 0; tb < 60; ++tb) {
      ITER(tb)
    }
    ITER(60)
    WAITV(4) BAR()
    DSL(61, 1, af1, bf1) WLGKM(6) MFMA8(af0, bf0)
    DSL(62, 0, af0, bf0) WLGKM(6) MFMA8(af1, bf1)
    WAITV(0) BAR()
    DSL(62, 1, af1, bf1) WLGKM(6) MFMA8(af0, bf0)
    DSL(63, 0, af0, bf0) WLGKM(6) MFMA8(af1, bf1)
    DSL(63, 1, af1, bf1) WLGKM(6) MFMA8(af0, bf0)
    WLGKM(0) MFMA8(af1, bf1)
  }

  // Epilogue (all variants store; only V3's final values persist).
  const int rbase = lk * 4;
  float swv[2];
  #pragma unroll
  for (int fj = 0; fj < 2; ++fj) swv[fj] = sw[n0 + wn * 64 + fj * 32 + lr];
  #pragma unroll
  for (int fi = 0; fi < 4; ++fi) {
    #pragma unroll
    for (int r = 0; r < 16; ++r) {
      const int row = (r & 3) + 8 * (r >> 2) + rbase;
      const int grow = m0 + wm * 128 + fi * 32 + row;
      const float sxv = sx[grow];
      float* orow = out + (size_t)grow * N + n0 + wn * 64 + lr;
      #pragma unroll
      for (int fj = 0; fj < 2; ++fj) {
        orow[fj * 32] = (float)acc[fi][fj][r] * sxv * swv[fj];
      }
    }
  }
}

extern "C" void kernel_launch(void* const* d_in, const int* in_sizes, int n_in,
                              void* d_out, int out_size, void* d_ws, size_t ws_size,
                              hipStream_t stream) {
  const float* x = (const float*)d_in[0];
  const int* w32 = (const int*)d_in[1];
  const float* wscale = (const float*)d_in[2];
  float* out = (float*)d_out;

  signed char* xq = (signed char*)d_ws;
  signed char* wq = xq + (size_t)M * K;
  float* sx = (float*)(wq + (size_t)N * K);

  pack_w_kernel<<<(N * K / 4 + 255) / 256, 256, 0, stream>>>(w32, wq);
  quant_x_kernel<<<M, 256, 0, stream>>>(x, xq, sx);
  // Diagnostic dispatches first (garbage math), correct kernel LAST.
  gemm_i8_kernel<1><<<NWG, 512, 131072, stream>>>(xq, wq, sx, wscale, out);
  gemm_i8_kernel<2><<<NWG, 512, 131072, stream>>>(xq, wq, sx, wscale, out);
  gemm_i8_kernel<3><<<NWG, 512, 131072, stream>>>(xq, wq, sx, wscale, out);
}

// Round 14
// 1068.097 us; speedup vs baseline: 4.5491x; 4.5491x over previous
//
#include <hip/hip_runtime.h>
#include <cstdint>
#include <cstddef>

typedef __attribute__((ext_vector_type(4))) int int32x4;
typedef __attribute__((ext_vector_type(16))) int int32x16;

#define DEVI __device__ __forceinline__

constexpr int M = 16384;
constexpr int N = 11008;
constexpr int K = 4096;
constexpr int BM = 256, BN = 256, BK = 64;   // BK in int8 elements (= bytes)
constexpr int NT_M = M / BM;                 // 64
constexpr int NT_N = N / BN;                 // 43
constexpr int NTILES = K / BK;               // 64
constexpr int NWG = NT_M * NT_N;             // 2752
constexpr int TILE_BYTES = BM * BK;          // 16 KB per tensor per slot

DEVI void gload_lds16(const void* gsrc, void* ldst) {
  __builtin_amdgcn_global_load_lds(
      (const __attribute__((address_space(1))) unsigned int*)gsrc,
      (__attribute__((address_space(3))) unsigned int*)ldst,
      16, 0, 0);
}

// ---- weight repack: int32 (harness int convention) -> int8 ----
__global__ __launch_bounds__(256) void pack_w_kernel(const int* __restrict__ w32,
                                                     signed char* __restrict__ w8) {
  const int idx = blockIdx.x * 256 + threadIdx.x;
  const int total4 = N * K / 4;
  if (idx < total4) {
    const int4 v = ((const int4*)w32)[idx];
    ((int*)w8)[idx] = (v.x & 255) | ((v.y & 255) << 8) |
                      ((v.z & 255) << 16) | ((v.w & 255) << 24);
  }
}

// ---- per-row symmetric int8 quantization of X ----
__global__ __launch_bounds__(256) void quant_x_kernel(const float* __restrict__ x,
                                                      signed char* __restrict__ xq,
                                                      float* __restrict__ sx) {
  const int row = blockIdx.x;
  const int t = threadIdx.x;
  const float4* xr = (const float4*)(x + (size_t)row * K);
  float4 v[4];
  float amax = 0.f;
  #pragma unroll
  for (int c = 0; c < 4; ++c) {
    v[c] = xr[c * 256 + t];
    amax = fmaxf(amax, fmaxf(fmaxf(fabsf(v[c].x), fabsf(v[c].y)),
                             fmaxf(fabsf(v[c].z), fabsf(v[c].w))));
  }
  __shared__ float red[256];
  red[t] = amax;
  __syncthreads();
  #pragma unroll
  for (int s = 128; s >= 1; s >>= 1) {
    if (t < s) red[t] = fmaxf(red[t], red[t + s]);
    __syncthreads();
  }
  const float am = fmaxf(red[0], 1e-20f);
  const float inv = 127.f / am;
  if (t == 0) sx[row] = am * (1.f / 127.f);
  int* xq32 = (int*)(xq + (size_t)row * K);
  #pragma unroll
  for (int c = 0; c < 4; ++c) {
    int q0 = min(127, max(-127, __float2int_rn(v[c].x * inv)));
    int q1 = min(127, max(-127, __float2int_rn(v[c].y * inv)));
    int q2 = min(127, max(-127, __float2int_rn(v[c].z * inv)));
    int q3 = min(127, max(-127, __float2int_rn(v[c].w * inv)));
    xq32[c * 256 + t] = (q0 & 255) | ((q1 & 255) << 8) |
                        ((q2 & 255) << 16) | ((q3 & 255) << 24);
  }
}

// ---- 256x256 int8 GEMM, ring-4 LDS, reg double-buffer, ANTI-PHASE halves ----
// R13 ablation: MFMA-only = 100% pipe (335 us/unit); +LDS reads = 614 us
// (full serialization: in-phase read-burst/MFMA alternation). Fix: waves 0-3
// process each tile sub0->sub1, waves 4-7 sub1->sub0 (exact int accumulation,
// order-free). Each SIMD hosts one wave of each half (w, w+4) -> one wave
// MFMAs while the other reads; LDS queue sees a steady stream, both pipes
// overlap. Zero extra registers. Base = R12 (band map + NT stores).
__global__ __launch_bounds__(512, 2) void gemm_i8_kernel(const signed char* __restrict__ aq,
                                                         const signed char* __restrict__ wq,
                                                         const float* __restrict__ sx,
                                                         const float* __restrict__ sw,
                                                         float* __restrict__ out) {
  extern __shared__ signed char smem[];            // 131072 B: 4 slots x 32 KB
  signed char* lsA = smem;                          // 4 slots x 16 KB (A)
  signed char* lsB = smem + 4 * TILE_BYTES;         // 4 slots x 16 KB (B)

  const int t = threadIdx.x;
  const int w = t >> 6;            // wave 0..7
  const int l = t & 63;

  // Band mapping (R12): bands of 4 nt (256 blocks = 1/CU); within a band,
  // XCD x owns mt in [8x, 8x+8) x the band's 4 nt. B band-slice L2-resident.
  const int bid = blockIdx.x;
  int mt, nt;
  {
    const int band = bid >> 8;
    const int ib = bid & 255;
    const int x = ib & 7;
    const int j = ib >> 3;
    if (band < 10) {
      mt = x * 8 + (j >> 2);
      nt = band * 4 + (j & 3);
    } else {
      mt = x * 8 + j / 3;
      nt = 40 + j % 3;
    }
  }
  const int m0 = mt * BM, n0 = nt * BN;

  // Staging: waves 0..3 stage A, waves 4..7 stage B; 4 x 16B chunks/thread.
  const bool stA = (w < 4);
  const signed char* src[4];
  int loff[4];
  #pragma unroll
  for (int c = 0; c < 4; ++c) {
    const int q = (w & 3) * 4 + c;
    const int row = (q & 3) * 64 + l;
    const int s = q >> 2;
    const signed char* base = stA ? (aq + (size_t)(m0 + row) * K)
                                  : (wq + (size_t)(n0 + row) * K);
    src[c] = base + s * 16;
    loff[c] = q * 1024;
  }

#define STAGE(tile)                                                           \
  {                                                                           \
    signed char* lbase = (stA ? lsA : lsB) + ((tile) & 3) * TILE_BYTES;       \
    const int koff = (tile) * BK;                                             \
    gload_lds16(src[0] + koff, lbase + loff[0]);                              \
    gload_lds16(src[1] + koff, lbase + loff[1]);                              \
    gload_lds16(src[2] + koff, lbase + loff[2]);                              \
    gload_lds16(src[3] + koff, lbase + loff[3]);                              \
  }

  // Wave output: 128x64 at (wm*128, wn*64); 4x2 frags of 32x32.
  const int wm = w >> 2, wn = w & 3;
  const int lk = l >> 5;
  const int lr = l & 31;
  int aOff[4], bOff[2];
  #pragma unroll
  for (int i = 0; i < 4; ++i)
    aOff[i] = lk * 4096 + (wm * 128 + i * 32 + lr) * 16;
  #pragma unroll
  for (int j = 0; j < 2; ++j)
    bOff[j] = lk * 4096 + (wn * 64 + j * 32 + lr) * 16;

  // Anti-phase: byte offset of the FIRST-consumed k-substep for this wave.
  const int sA_off = (w < 4) ? 0 : 8192;     // waves 0-3: sub0 first
  const int sB_off = 8192 - sA_off;          // waves 4-7: sub1 first

  int32x16 acc[4][2] = {};
  int32x4 af0[4], bf0[2], af1[4], bf1[2];

#define DSL(tile, soff, AF, BF)                                               \
  {                                                                           \
    const signed char* pA = lsA + ((tile) & 3) * TILE_BYTES + (soff);         \
    const signed char* pB = lsB + ((tile) & 3) * TILE_BYTES + (soff);         \
    AF[0] = *(const int32x4*)(pA + aOff[0]);                                  \
    AF[1] = *(const int32x4*)(pA + aOff[1]);                                  \
    AF[2] = *(const int32x4*)(pA + aOff[2]);                                  \
    AF[3] = *(const int32x4*)(pA + aOff[3]);                                  \
    BF[0] = *(const int32x4*)(pB + bOff[0]);                                  \
    BF[1] = *(const int32x4*)(pB + bOff[1]);                                  \
  }

#define MFMA8(AF, BF)                                                         \
  __builtin_amdgcn_s_setprio(1);                                              \
  {                                                                           \
    _Pragma("unroll")                                                         \
    for (int i = 0; i < 4; ++i) {                                             \
      acc[i][0] = __builtin_amdgcn_mfma_i32_32x32x32_i8(AF[i], BF[0],         \
                                                        acc[i][0], 0, 0, 0);  \
      acc[i][1] = __builtin_amdgcn_mfma_i32_32x32x32_i8(AF[i], BF[1],         \
                                                        acc[i][1], 0, 0, 0);  \
    }                                                                         \
  }                                                                           \
  __builtin_amdgcn_s_setprio(0);

#define WAITV(n) asm volatile("s_waitcnt vmcnt(" #n ")" ::: "memory");
#define WLGKM(n)                                                              \
  asm volatile("s_waitcnt lgkmcnt(" #n ")" ::: "memory");                     \
  __builtin_amdgcn_sched_barrier(0);
#define BAR() __builtin_amdgcn_s_barrier();

#define ITER(tt)                                                              \
  WAITV(4)                      /* tile tt+1 landed (tt+2 in flight) */        \
  BAR()                         /* publish tt+1; tt-1 reads retired */         \
  STAGE(tt + 3)                 /* overwrites slot (tt-1)&3 */                 \
  DSL(tt, sB_off, af1, bf1)     /* this wave's SECOND half of tile tt */       \
  WLGKM(6)                                                                    \
  MFMA8(af0, bf0)               /* FIRST half (loaded previous iter) */        \
  DSL(tt + 1, sA_off, af0, bf0) /* next tile's first half */                   \
  WLGKM(6)                                                                    \
  MFMA8(af1, bf1)               /* second half */

  // Prologue: stage tiles 0..2; tile 0 landed -> read this wave's first half.
  STAGE(0) STAGE(1) STAGE(2)
  WAITV(8)
  BAR()
  DSL(0, sA_off, af0, bf0)

  #pragma unroll 4
  for (int tb = 0; tb < 60; ++tb) {
    ITER(tb)
  }
  ITER(60)   // stages tile 63 (last)
  // tt = 61
  WAITV(4) BAR()
  DSL(61, sB_off, af1, bf1) WLGKM(6) MFMA8(af0, bf0)
  DSL(62, sA_off, af0, bf0) WLGKM(6) MFMA8(af1, bf1)
  // tt = 62
  WAITV(0) BAR()
  DSL(62, sB_off, af1, bf1) WLGKM(6) MFMA8(af0, bf0)
  DSL(63, sA_off, af0, bf0) WLGKM(6) MFMA8(af1, bf1)
  // tt = 63
  DSL(63, sB_off, af1, bf1) WLGKM(6) MFMA8(af0, bf0)
  WLGKM(0) MFMA8(af1, bf1)

  // Epilogue: dequant + non-temporal store.
  // 32x32 C/D map: col = lane&31, row = (r&3) + 8*(r>>2) + 4*(lane>>5).
  const int rbase = lk * 4;
  float swv[2];
  #pragma unroll
  for (int fj = 0; fj < 2; ++fj) swv[fj] = sw[n0 + wn * 64 + fj * 32 + lr];
  #pragma unroll
  for (int fi = 0; fi < 4; ++fi) {
    #pragma unroll
    for (int r = 0; r < 16; ++r) {
      const int row = (r & 3) + 8 * (r >> 2) + rbase;
      const int grow = m0 + wm * 128 + fi * 32 + row;
      const float sxv = sx[grow];
      float* orow = out + (size_t)grow * N + n0 + wn * 64 + lr;
      #pragma unroll
      for (int fj = 0; fj < 2; ++fj) {
        __builtin_nontemporal_store((float)acc[fi][fj][r] * sxv * swv[fj],
                                    &orow[fj * 32]);
      }
    }
  }
}

extern "C" void kernel_launch(void* const* d_in, const int* in_sizes, int n_in,
                              void* d_out, int out_size, void* d_ws, size_t ws_size,
                              hipStream_t stream) {
  const float* x = (const float*)d_in[0];
  const int* w32 = (const int*)d_in[1];
  const float* wscale = (const float*)d_in[2];
  float* out = (float*)d_out;

  signed char* xq = (signed char*)d_ws;
  signed char* wq = xq + (size_t)M * K;
  float* sx = (float*)(wq + (size_t)N * K);

  pack_w_kernel<<<(N * K / 4 + 255) / 256, 256, 0, stream>>>(w32, wq);
  quant_x_kernel<<<M, 256, 0, stream>>>(x, xq, sx);
  gemm_i8_kernel<<<NWG, 512, 131072, stream>>>(xq, wq, sx, wscale, out);
}